// Round 7
// baseline (495.930 us; speedup 1.0000x reference)
//
#include <hip/hip_runtime.h>

// Encoder: B=512, T=128, N=128, H=256
// Round 7: k_rnn restructured — 4 waves/block, A-operand = Wh^T resident in
// VGPRs (D rows = j -> packed b64 h-writes), Q-GEMM removed from the serial
// loop; k_rnn stores H (f16). Q is re-fused into k_attn as a per-block
// 32x128x256 MFMA GEMM over the H slice the block already loads.
//  k_prep_w: Wxt[256][128], W2t[128][256], W1t[128][128], Wht[256][256] f16 [n][k]
//  k_gemm<K,MODE>: C = A @ Bt^T via mfma_f32_16x16x32_f16, Mt=64, Nt=128.
//  k_rnn : 32 blocks x 256 thr. h_{t+1} = tanh(xw_t + h_t@Wh); lgkm-only barrier.
//  k_attn: Q = exp2(C2L*(H@W2+b2)) (MFMA, in-LDS), then
//          e_i = sum_tau (-2wv)*rcp(P*Q+1); softmax over i; out = data*alpha.
// Workspace (f32 offsets): P 0 | xw 8388608 | H(hf) 25165824 | wts(hf) 33554432
//   => ~134.5 MB.

#define C2L 2.8853900817779268f   // 2*log2(e)
#define L2E 1.4426950408889634f   // log2(e)

typedef _Float16 hf;
typedef _Float16 hf4 __attribute__((ext_vector_type(4)));
typedef _Float16 hf8 __attribute__((ext_vector_type(8)));
typedef float f32x4 __attribute__((ext_vector_type(4)));

__device__ __forceinline__ float fast_exp2(float x){
#if __has_builtin(__builtin_amdgcn_exp2f)
  return __builtin_amdgcn_exp2f(x);
#else
  return exp2f(x);
#endif
}
__device__ __forceinline__ float fast_rcp(float x){
#if __has_builtin(__builtin_amdgcn_rcpf)
  return __builtin_amdgcn_rcpf(x);
#else
  return 1.f/x;
#endif
}
// Block barrier draining only LDS ops (not vmcnt): global prefetch loads and
// stores stay in flight. Safe when cross-thread data at the barrier is LDS.
__device__ __forceinline__ void sync_lds_only(){
  asm volatile("s_waitcnt lgkmcnt(0)" ::: "memory");
  __builtin_amdgcn_s_barrier();
}

// ---------------- weight prep: f32 [k][n] -> f16 [n][k] ----------------
__global__ __launch_bounds__(256) void k_prep_w(const float* __restrict__ Wx,
    const float* __restrict__ W2, const float* __restrict__ W1,
    const float* __restrict__ Wh, hf* __restrict__ wts){
  int tid = blockIdx.x*256 + threadIdx.x;   // 576 blocks -> 147456 threads
  if (tid < 32768){                          // Wxt[n<256][k<128]
    int n = tid >> 7, k = tid & 127;
    wts[tid] = (hf)Wx[k*256 + n];
  } else if (tid < 65536){                   // W2t[n<128][k<256]
    int t2 = tid - 32768;
    int n = t2 >> 8, k = t2 & 255;
    wts[tid] = (hf)W2[k*128 + n];
  } else if (tid < 81920){                   // W1t[n<128][k<128]
    int t3 = tid - 65536;
    int n = t3 >> 7, k = t3 & 127;
    wts[tid] = (hf)W1[k*128 + n];
  } else {                                   // Wht[n<256][k<256]
    int t4 = tid - 81920;
    int n = t4 >> 8, k = t4 & 255;
    wts[tid] = (hf)Wh[k*256 + n];
  }
}

// ---------------- unified MFMA GEMM (xw, pre) ----------------
// block = 256 thr (4 waves). Tile: M=64 (wave strip 16), N=128, K chunked by 128.
template<int K, int MODE>
__global__ __launch_bounds__(256) void k_gemm(const void* __restrict__ Asrc,
    const hf* __restrict__ Bt, const float* __restrict__ bias,
    float* __restrict__ Cout){
  constexpr int SA = 136;
  __shared__ alignas(16) hf As[64*SA];
  __shared__ alignas(16) hf Bs[128*SA];
  const int tid = threadIdx.x;
  const int w = tid >> 6, lane = tid & 63;
  const int c = lane & 15, q = lane >> 4;
  const int bx = blockIdx.x;
  const int col0 = (MODE==0) ? blockIdx.y*128 : 0;

  float br[8];
  #pragma unroll
  for (int ni=0; ni<8; ni++) br[ni] = bias[col0 + ni*16 + c];

  f32x4 acc[8];
  #pragma unroll
  for (int ni=0; ni<8; ni++) acc[ni] = (f32x4){0.f,0.f,0.f,0.f};

  for (int kc=0; kc<K/128; kc++){
    if (MODE == 0){
      const float* A = (const float*)Asrc + (long)bx*64*128;
      #pragma unroll
      for (int v=0; v<8; v++){
        int f4 = v*256 + tid;
        int m = f4 >> 5, k4 = (f4 & 31)*4;
        float4 d = *(const float4*)&A[m*128 + k4];
        hf4 h = {(hf)d.x,(hf)d.y,(hf)d.z,(hf)d.w};
        *(hf4*)&As[m*SA + k4] = h;
      }
    } else {
      const float* A = (const float*)Asrc + (long)(bx>>1)*16384;
      const int i0 = (bx & 1)*64;
      #pragma unroll
      for (int v=0; v<8; v++){
        int f4 = v*256 + tid;
        int t = f4 >> 4, i4 = (f4 & 15)*4;
        float4 d = *(const float4*)&A[t*128 + i0 + i4];
        As[(i4+0)*SA + t] = (hf)d.x;
        As[(i4+1)*SA + t] = (hf)d.y;
        As[(i4+2)*SA + t] = (hf)d.z;
        As[(i4+3)*SA + t] = (hf)d.w;
      }
    }
    #pragma unroll
    for (int v=0; v<8; v++){
      int f8 = v*256 + tid;
      int n = f8 >> 4, k8 = (f8 & 15)*8;
      *(hf8*)&Bs[n*SA + k8] = *(const hf8*)&Bt[(col0+n)*K + kc*128 + k8];
    }
    __syncthreads();
    #pragma unroll
    for (int kk=0; kk<4; kk++){
      hf8 a = *(const hf8*)&As[(w*16 + c)*SA + kk*32 + q*8];
      #pragma unroll
      for (int ni=0; ni<8; ni++){
        hf8 b = *(const hf8*)&Bs[(ni*16 + c)*SA + kk*32 + q*8];
        acc[ni] = __builtin_amdgcn_mfma_f32_16x16x32_f16(a, b, acc[ni], 0, 0, 0);
      }
    }
    __syncthreads();
  }
  #pragma unroll
  for (int ni=0; ni<8; ni++){
    #pragma unroll
    for (int r=0; r<4; r++){
      int rloc = w*16 + q*4 + r;
      int col = col0 + ni*16 + c;
      float val = acc[ni][r] + br[ni];
      int addr;
      if (MODE == 0){
        int R = bx*64 + rloc;
        int b_ = R >> 7, t_ = R & 127;
        addr = (t_*512 + b_)*256 + col;
      } else {
        int b_ = bx >> 1, i_ = (bx & 1)*64 + rloc;
        addr = b_*16384 + i_*128 + col;
        val = fast_exp2(C2L*val);
      }
      Cout[addr] = val;
    }
  }
}

// ---------------- MFMA recurrence ----------------
// grid 32 x 256 thr (4 waves). Block owns 16 batches (N=16 MFMA cols).
// Wave w owns j in [w*64, w*64+64): A-op = Wh^T[j][k] resident (32 hf8 frags,
// 128 VGPR). B-op = h_t[batch=c][k] from LDS (8 ds_read_b128/wave, shared
// pattern). D[row=j_local][col=batch] -> thread holds 4 CONTIGUOUS j for
// batch c -> packed b64 LDS write + b64 global H store (f16).
// Barrier is lgkm-only: xw prefetch / H stores float across it.
__global__ __launch_bounds__(256, 1) void k_rnn(const float* __restrict__ h0,
    const hf* __restrict__ Wht, const float* __restrict__ xw,
    hf* __restrict__ H){
  constexpr int SK = 264;
  __shared__ alignas(16) hf hs[2][16*SK];
  const int tid = threadIdx.x;
  const int w = tid >> 6, lane = tid & 63;
  const int c = lane & 15, q = lane >> 4;
  const int bb0 = blockIdx.x*16;
  const int jw = w*64;

  // resident Wh^T A-frags
  hf8 af[4][8];
  #pragma unroll
  for (int mt=0; mt<4; mt++)
    #pragma unroll
    for (int kc=0; kc<8; kc++)
      af[mt][kc] = *(const hf8*)&Wht[(jw + mt*16 + c)*256 + kc*32 + q*8];

  // stage h0 (16 rows x 256 f32 -> f16)
  {
    int m = tid >> 4, k0 = (tid & 15)*16;
    const float* src = h0 + (bb0 + m)*256 + k0;
    float4 a0 = *(const float4*)&src[0];
    float4 a1 = *(const float4*)&src[4];
    float4 a2 = *(const float4*)&src[8];
    float4 a3 = *(const float4*)&src[12];
    hf8 h0v = {(hf)a0.x,(hf)a0.y,(hf)a0.z,(hf)a0.w,(hf)a1.x,(hf)a1.y,(hf)a1.z,(hf)a1.w};
    hf8 h1v = {(hf)a2.x,(hf)a2.y,(hf)a2.z,(hf)a2.w,(hf)a3.x,(hf)a3.y,(hf)a3.z,(hf)a3.w};
    *(hf8*)&hs[0][m*SK + k0]     = h0v;
    *(hf8*)&hs[0][m*SK + k0 + 8] = h1v;
  }

  // xw prefetch (t=0): thread rows: batch=c, j = jw + mt*16 + q*4..+4
  float4 xwp[2][4];
  #pragma unroll
  for (int mt=0; mt<4; mt++)
    xwp[0][mt] = *(const float4*)&xw[(bb0 + c)*256 + jw + mt*16 + q*4];
  sync_lds_only();

  for (int t=0; t<128; t++){
    const int cur = t & 1;
    if (t < 127){
      #pragma unroll
      for (int mt=0; mt<4; mt++)
        xwp[cur^1][mt] = *(const float4*)&xw[((t+1)*512 + bb0 + c)*256 + jw + mt*16 + q*4];
    }
    f32x4 acc[4];
    #pragma unroll
    for (int mt=0; mt<4; mt++) acc[mt] = (f32x4){0.f,0.f,0.f,0.f};
    const hf* hrow = &hs[cur][0] + c*SK + q*8;
    #pragma unroll
    for (int kc=0; kc<8; kc++){
      hf8 bfrag = *(const hf8*)(hrow + kc*32);
      #pragma unroll
      for (int mt=0; mt<4; mt++)
        acc[mt] = __builtin_amdgcn_mfma_f32_16x16x32_f16(af[mt][kc], bfrag, acc[mt], 0,0,0);
    }
    #pragma unroll
    for (int mt=0; mt<4; mt++){
      float4 xv = xwp[cur][mt];
      float xa[4] = {xv.x, xv.y, xv.z, xv.w};
      hf4 hh;
      #pragma unroll
      for (int r=0; r<4; r++){
        float v = acc[mt][r] + xa[r];
        float e2 = fast_exp2(v*C2L);
        hh[r] = (hf)(1.f - 2.f*fast_rcp(e2 + 1.f));
      }
      *(hf4*)&hs[cur^1][c*SK + jw + mt*16 + q*4] = hh;
      *(hf4*)&H[(long)(t*512 + bb0 + c)*256 + jw + mt*16 + q*4] = hh;
    }
    sync_lds_only();
  }
}

// ---------------- attention: fused Q-GEMM + softmax + scale ----------------
// grid (512 b, 4 t-tiles), 256 thr (4 waves), __launch_bounds__(256,4).
// Phase 1: stage H[t0..t0+32][b][:] (f16, 16.9KB LDS).
// Phase 2: Q = exp2(C2L*(H@W2+b2)) via MFMA (wave w: m-tile w&1, n-tiles
//          (w>>1)*4..+4; B-frags streamed from L1/L2). qs overlays Hs.
// Phase 3: r6 attention loop (pairwise rcp, softmax without max, scale).
__global__ __launch_bounds__(256, 4) void k_attn(const float* __restrict__ P,
    const hf* __restrict__ H, const hf* __restrict__ W2t,
    const float* __restrict__ b2, const float* __restrict__ Wv,
    const float* __restrict__ data, float* __restrict__ out){
  __shared__ alignas(16) unsigned char hq[32*264*2];  // Hs (16.9KB) / qs (16KB)
  __shared__ alignas(16) float wvs[128];
  __shared__ alignas(16) float epart[2][2][4][128];   // 16KB
  __shared__ float red[2][4][2];
  hf* Hs = (hf*)hq;
  float* qs = (float*)hq;
  constexpr int SH = 264;
  const int b = blockIdx.x, tile = blockIdx.y;
  const int tid = threadIdx.x;
  const int w = tid >> 6, lane = tid & 63;
  const int c = lane & 15, q = lane >> 4;
  const int i = tid & 127, hl = tid >> 7;
  const int t0 = tile*32;
  if (tid < 128) wvs[tid] = -2.f*Wv[tid];
  // ---- stage H slice: 32 rows x 256 hf ----
  {
    int tt = tid >> 3, seg = (tid & 7)*32;
    const hf* src = H + (long)((t0+tt)*512 + b)*256 + seg;
    #pragma unroll
    for (int v=0; v<4; v++)
      *(hf8*)&Hs[tt*SH + seg + v*8] = *(const hf8*)&src[v*8];
  }
  __syncthreads();
  // ---- Q-GEMM: M=32(t) x N=128(tau) x K=256 ----
  const int mt = w & 1, ng = (w >> 1)*4;    // n-tiles ng..ng+3
  float b2v[4];
  #pragma unroll
  for (int ntl=0; ntl<4; ntl++) b2v[ntl] = b2[(ng+ntl)*16 + c];
  f32x4 qacc[4];
  #pragma unroll
  for (int ntl=0; ntl<4; ntl++) qacc[ntl] = (f32x4){0.f,0.f,0.f,0.f};
  #pragma unroll
  for (int kc=0; kc<8; kc++){
    hf8 a = *(const hf8*)&Hs[(mt*16 + c)*SH + kc*32 + q*8];
    #pragma unroll
    for (int ntl=0; ntl<4; ntl++){
      hf8 bf = *(const hf8*)&W2t[((ng+ntl)*16 + c)*256 + kc*32 + q*8];
      qacc[ntl] = __builtin_amdgcn_mfma_f32_16x16x32_f16(a, bf, qacc[ntl], 0,0,0);
    }
  }
  __syncthreads();                          // Hs reads complete
  #pragma unroll
  for (int ntl=0; ntl<4; ntl++){
    #pragma unroll
    for (int r=0; r<4; r++){
      int tloc = mt*16 + q*4 + r;
      int tau = (ng+ntl)*16 + c;
      qs[tloc*128 + tau] = fast_exp2(C2L*(qacc[ntl][r] + b2v[ntl]));
    }
  }
  // ---- P rows into registers ----
  float4 p4[16];
  const float* prow = P + b*16384 + i*128 + hl*64;
  #pragma unroll
  for (int v=0; v<16; v++) p4[v] = *(const float4*)&prow[v*4];
  __syncthreads();
  // ---- attention loop ----
  for (int tp=0; tp<8; tp++){
    const int pp = tp & 1;
    const float* q0r = &qs[(4*tp)*128   + hl*64];
    const float* q1r = &qs[(4*tp+1)*128 + hl*64];
    const float* q2r = &qs[(4*tp+2)*128 + hl*64];
    const float* q3r = &qs[(4*tp+3)*128 + hl*64];
    const float* wvr = &wvs[hl*64];
    float acc0=0.f, acc1=0.f, acc2=0.f, acc3=0.f;
    #pragma unroll
    for (int m=0; m<16; m++){
      float4 Pv = p4[m];
      float4 wv = *(const float4*)&wvr[m*4];
      {
        float4 qq = *(const float4*)&q0r[m*4];
        float u = fmaf(Pv.x, qq.x, 1.f), v = fmaf(Pv.y, qq.y, 1.f);
        float n = fmaf(wv.x, v, wv.y*u);
        acc0 = fmaf(n, fast_rcp(u*v), acc0);
        float u2 = fmaf(Pv.z, qq.z, 1.f), v2 = fmaf(Pv.w, qq.w, 1.f);
        float n2 = fmaf(wv.z, v2, wv.w*u2);
        acc0 = fmaf(n2, fast_rcp(u2*v2), acc0);
      }
      {
        float4 qq = *(const float4*)&q1r[m*4];
        float u = fmaf(Pv.x, qq.x, 1.f), v = fmaf(Pv.y, qq.y, 1.f);
        float n = fmaf(wv.x, v, wv.y*u);
        acc1 = fmaf(n, fast_rcp(u*v), acc1);
        float u2 = fmaf(Pv.z, qq.z, 1.f), v2 = fmaf(Pv.w, qq.w, 1.f);
        float n2 = fmaf(wv.z, v2, wv.w*u2);
        acc1 = fmaf(n2, fast_rcp(u2*v2), acc1);
      }
      {
        float4 qq = *(const float4*)&q2r[m*4];
        float u = fmaf(Pv.x, qq.x, 1.f), v = fmaf(Pv.y, qq.y, 1.f);
        float n = fmaf(wv.x, v, wv.y*u);
        acc2 = fmaf(n, fast_rcp(u*v), acc2);
        float u2 = fmaf(Pv.z, qq.z, 1.f), v2 = fmaf(Pv.w, qq.w, 1.f);
        float n2 = fmaf(wv.z, v2, wv.w*u2);
        acc2 = fmaf(n2, fast_rcp(u2*v2), acc2);
      }
      {
        float4 qq = *(const float4*)&q3r[m*4];
        float u = fmaf(Pv.x, qq.x, 1.f), v = fmaf(Pv.y, qq.y, 1.f);
        float n = fmaf(wv.x, v, wv.y*u);
        acc3 = fmaf(n, fast_rcp(u*v), acc3);
        float u2 = fmaf(Pv.z, qq.z, 1.f), v2 = fmaf(Pv.w, qq.w, 1.f);
        float n2 = fmaf(wv.z, v2, wv.w*u2);
        acc3 = fmaf(n2, fast_rcp(u2*v2), acc3);
      }
    }
    epart[pp][hl][0][i] = acc0;
    epart[pp][hl][1][i] = acc1;
    epart[pp][hl][2][i] = acc2;
    epart[pp][hl][3][i] = acc3;
    __syncthreads();
    const int g = tid >> 7;
    float pe[2];
    #pragma unroll
    for (int s=0; s<2; s++){
      int tl = g + 2*s;
      float e = epart[pp][0][tl][i] + epart[pp][1][tl][i];
      pe[s] = fast_exp2(e*L2E);
      float sm = pe[s];
      #pragma unroll
      for (int off=32; off; off>>=1) sm += __shfl_xor(sm, off);
      if ((tid & 63) == 0) red[pp][tl][(tid>>6)&1] = sm;
    }
    __syncthreads();
    #pragma unroll
    for (int s=0; s<2; s++){
      int tl = g + 2*s;
      float ssum = red[pp][tl][0] + red[pp][tl][1];
      float alpha = pe[s] * fast_rcp(ssum);
      int t = t0 + 4*tp + tl;
      int base = (t*512 + b)*128 + i;
      out[base] = data[base]*alpha;
    }
  }
}

extern "C" void kernel_launch(void* const* d_in, const int* in_sizes, int n_in,
                              void* d_out, int out_size, void* d_ws, size_t ws_size,
                              hipStream_t stream) {
  const float* data = (const float*)d_in[0];
  const float* h0   = (const float*)d_in[1];
  const float* Wx   = (const float*)d_in[2];
  const float* Wh   = (const float*)d_in[3];
  const float* bb   = (const float*)d_in[4];
  const float* W1   = (const float*)d_in[5];
  const float* b1   = (const float*)d_in[6];
  const float* W2   = (const float*)d_in[7];
  const float* b2   = (const float*)d_in[8];
  const float* Wv   = (const float*)d_in[9];
  // d_in[10] = bv: softmax-invariant constant, dropped. d_in[11] = n (128).
  float* wsp = (float*)d_ws;
  float* P    = wsp;                        //  8,388,608 f
  float* xw   = wsp + 8388608;              // 16,777,216 f
  hf*    Hbuf = (hf*)(wsp + 25165824);      // 16,777,216 hf
  hf*    wts  = (hf*)(wsp + 33554432);      // 147,456 hf
  hf*    Wxt  = wts;                        // [256][128]
  hf*    W2t  = wts + 32768;                // [128][256]
  hf*    W1t  = wts + 65536;                // [128][128]
  hf*    Wht  = wts + 81920;                // [256][256]
  float* out = (float*)d_out;

  hipLaunchKernelGGL(k_prep_w, dim3(576), dim3(256), 0, stream, Wx, W2, W1, Wh, wts);
  hipLaunchKernelGGL((k_gemm<128,0>), dim3(1024,2), dim3(256), 0, stream,
                     (const void*)data, Wxt, bb, xw);
  hipLaunchKernelGGL((k_gemm<128,2>), dim3(1024),   dim3(256), 0, stream,
                     (const void*)data, W1t, b1, P);
  hipLaunchKernelGGL(k_rnn, dim3(32), dim3(256), 0, stream, h0, Wht, xw, Hbuf);
  hipLaunchKernelGGL(k_attn, dim3(512, 4), dim3(256), 0, stream,
                     P, Hbuf, W2t, b2, Wv, data, out);
}

// Round 8
// 488.181 us; speedup vs baseline: 1.0159x; 1.0159x over previous
//
#include <hip/hip_runtime.h>

// Encoder: B=512, T=128, N=128, H=256
// Round 8: k_rnn weight fragments PINNED in VGPRs via asm("+v") — r7's
// VGPR=104 proved the compiler was re-loading Wh^T from global every step
// (2000+ cyc/step). P-GEMM fused into the same launch (blocks >= 32) to
// overlap with the 32-CU recurrence.
//  k_prep_w: Wxt[256][128], W2t[128][256], W1t[128][128], Wht[256][256] f16 [n][k]
//  k_gemm<128,0>: xw = data @ Wx + b  (MFMA, Mt=64, Nt=128)
//  k_rnn_pre: blk<32: h_{t+1}=tanh(xw_t+h_t@Wh) (MFMA, pinned weights,
//             lgkm-only barrier, H stored f16);
//             blk>=32: P[b][i][tau]=exp2(C2L*(data^T@W1+b1)) (MFMA).
//  k_attn: Q = exp2(C2L*(H@W2+b2)) (MFMA in-LDS), then
//          e_i = sum_tau (-2wv)*rcp(P*Q+1); softmax over i; out = data*alpha.
// Workspace (f32 offsets): P 0 | xw 8388608 | H(hf) 25165824 | wts(hf) 33554432

#define C2L 2.8853900817779268f   // 2*log2(e)
#define L2E 1.4426950408889634f   // log2(e)

typedef _Float16 hf;
typedef _Float16 hf4 __attribute__((ext_vector_type(4)));
typedef _Float16 hf8 __attribute__((ext_vector_type(8)));
typedef float f32x4 __attribute__((ext_vector_type(4)));

__device__ __forceinline__ float fast_exp2(float x){
#if __has_builtin(__builtin_amdgcn_exp2f)
  return __builtin_amdgcn_exp2f(x);
#else
  return exp2f(x);
#endif
}
__device__ __forceinline__ float fast_rcp(float x){
#if __has_builtin(__builtin_amdgcn_rcpf)
  return __builtin_amdgcn_rcpf(x);
#else
  return 1.f/x;
#endif
}
// Block barrier draining only LDS ops (not vmcnt): global prefetch loads and
// stores stay in flight. Safe when cross-thread data at the barrier is LDS.
__device__ __forceinline__ void sync_lds_only(){
  asm volatile("s_waitcnt lgkmcnt(0)" ::: "memory");
  __builtin_amdgcn_s_barrier();
}

// ---------------- weight prep: f32 [k][n] -> f16 [n][k] ----------------
__global__ __launch_bounds__(256) void k_prep_w(const float* __restrict__ Wx,
    const float* __restrict__ W2, const float* __restrict__ W1,
    const float* __restrict__ Wh, hf* __restrict__ wts){
  int tid = blockIdx.x*256 + threadIdx.x;   // 576 blocks -> 147456 threads
  if (tid < 32768){                          // Wxt[n<256][k<128]
    int n = tid >> 7, k = tid & 127;
    wts[tid] = (hf)Wx[k*256 + n];
  } else if (tid < 65536){                   // W2t[n<128][k<256]
    int t2 = tid - 32768;
    int n = t2 >> 8, k = t2 & 255;
    wts[tid] = (hf)W2[k*128 + n];
  } else if (tid < 81920){                   // W1t[n<128][k<128]
    int t3 = tid - 65536;
    int n = t3 >> 7, k = t3 & 127;
    wts[tid] = (hf)W1[k*128 + n];
  } else {                                   // Wht[n<256][k<256]
    int t4 = tid - 81920;
    int n = t4 >> 8, k = t4 & 255;
    wts[tid] = (hf)Wh[k*256 + n];
  }
}

// ---------------- MFMA GEMM for xw ----------------
// block = 256 thr (4 waves). Tile: M=64 (wave strip 16), N=128, K=128.
template<int K, int MODE>
__global__ __launch_bounds__(256) void k_gemm(const void* __restrict__ Asrc,
    const hf* __restrict__ Bt, const float* __restrict__ bias,
    float* __restrict__ Cout){
  constexpr int SA = 136;
  __shared__ alignas(16) hf As[64*SA];
  __shared__ alignas(16) hf Bs[128*SA];
  const int tid = threadIdx.x;
  const int w = tid >> 6, lane = tid & 63;
  const int c = lane & 15, q = lane >> 4;
  const int bx = blockIdx.x;
  const int col0 = (MODE==0) ? blockIdx.y*128 : 0;

  float br[8];
  #pragma unroll
  for (int ni=0; ni<8; ni++) br[ni] = bias[col0 + ni*16 + c];

  f32x4 acc[8];
  #pragma unroll
  for (int ni=0; ni<8; ni++) acc[ni] = (f32x4){0.f,0.f,0.f,0.f};

  for (int kc=0; kc<K/128; kc++){
    {
      const float* A = (const float*)Asrc + (long)bx*64*128;
      #pragma unroll
      for (int v=0; v<8; v++){
        int f4 = v*256 + tid;
        int m = f4 >> 5, k4 = (f4 & 31)*4;
        float4 d = *(const float4*)&A[m*128 + k4];
        hf4 h = {(hf)d.x,(hf)d.y,(hf)d.z,(hf)d.w};
        *(hf4*)&As[m*SA + k4] = h;
      }
    }
    #pragma unroll
    for (int v=0; v<8; v++){
      int f8 = v*256 + tid;
      int n = f8 >> 4, k8 = (f8 & 15)*8;
      *(hf8*)&Bs[n*SA + k8] = *(const hf8*)&Bt[(col0+n)*K + kc*128 + k8];
    }
    __syncthreads();
    #pragma unroll
    for (int kk=0; kk<4; kk++){
      hf8 a = *(const hf8*)&As[(w*16 + c)*SA + kk*32 + q*8];
      #pragma unroll
      for (int ni=0; ni<8; ni++){
        hf8 b = *(const hf8*)&Bs[(ni*16 + c)*SA + kk*32 + q*8];
        acc[ni] = __builtin_amdgcn_mfma_f32_16x16x32_f16(a, b, acc[ni], 0, 0, 0);
      }
    }
    __syncthreads();
  }
  #pragma unroll
  for (int ni=0; ni<8; ni++){
    #pragma unroll
    for (int r=0; r<4; r++){
      int rloc = w*16 + q*4 + r;
      int col = col0 + ni*16 + c;
      float val = acc[ni][r] + br[ni];
      int R = bx*64 + rloc;
      int b_ = R >> 7, t_ = R & 127;
      Cout[(t_*512 + b_)*256 + col] = val;
    }
  }
}

// ---------------- fused: MFMA recurrence (blk<32) + P-GEMM (blk>=32) -------
// RNN: 32 blocks x 256 thr (4 waves), 16 batches/block. Wave w owns j in
// [w*64,+64): A-op = Wh^T resident, PINNED via asm (32 f32x4 = 128 VGPR).
// B-op = h_t[batch][k] from LDS. D[row=j][col=batch] -> 4 contiguous j per
// thread -> packed b64 LDS write + b64 global H store (f16). lgkm-only barrier.
// PRE: P-GEMM (M=64 i, N=128 tau, K=128 t) with data^T staged A.
__global__ __launch_bounds__(256) void k_rnn_pre(
    const float* __restrict__ h0, const hf* __restrict__ Wht,
    const float* __restrict__ xw, hf* __restrict__ H,
    const float* __restrict__ data, const hf* __restrict__ W1t,
    const float* __restrict__ b1, float* __restrict__ P){
  __shared__ alignas(16) unsigned char smem[52224];
  const int tid = threadIdx.x;
  const int w = tid >> 6, lane = tid & 63;
  const int c = lane & 15, q = lane >> 4;

  if (blockIdx.x < 32){
    // =================== RNN path ===================
    constexpr int SK = 264;
    hf* hs0 = (hf*)smem;                 // [16*SK]
    hf* hs1 = (hf*)smem + 16*SK;
    const int bb0 = blockIdx.x*16;
    const int jw = w*64;

    // resident Wh^T A-frags, pinned
    f32x4 afr[32];
    #pragma unroll
    for (int mt=0; mt<4; mt++)
      #pragma unroll
      for (int kc=0; kc<8; kc++)
        afr[mt*8+kc] = *(const f32x4*)&Wht[(jw + mt*16 + c)*256 + kc*32 + q*8];
    #pragma unroll
    for (int u=0; u<32; u++) asm volatile("" : "+v"(afr[u]));

    // stage h0 (16 rows x 256 f32 -> f16)
    {
      int m = tid >> 4, k0 = (tid & 15)*16;
      const float* src = h0 + (bb0 + m)*256 + k0;
      float4 a0 = *(const float4*)&src[0];
      float4 a1 = *(const float4*)&src[4];
      float4 a2 = *(const float4*)&src[8];
      float4 a3 = *(const float4*)&src[12];
      hf8 h0v = {(hf)a0.x,(hf)a0.y,(hf)a0.z,(hf)a0.w,(hf)a1.x,(hf)a1.y,(hf)a1.z,(hf)a1.w};
      hf8 h1v = {(hf)a2.x,(hf)a2.y,(hf)a2.z,(hf)a2.w,(hf)a3.x,(hf)a3.y,(hf)a3.z,(hf)a3.w};
      *(hf8*)&hs0[m*SK + k0]     = h0v;
      *(hf8*)&hs0[m*SK + k0 + 8] = h1v;
    }

    float4 xwp[2][4];
    #pragma unroll
    for (int mt=0; mt<4; mt++)
      xwp[0][mt] = *(const float4*)&xw[(bb0 + c)*256 + jw + mt*16 + q*4];
    sync_lds_only();

    for (int t=0; t<128; t++){
      const int cur = t & 1;
      hf* hcur = cur ? hs1 : hs0;
      hf* hnxt = cur ? hs0 : hs1;
      if (t < 127){
        #pragma unroll
        for (int mt=0; mt<4; mt++)
          xwp[cur^1][mt] = *(const float4*)&xw[((t+1)*512 + bb0 + c)*256 + jw + mt*16 + q*4];
      }
      f32x4 acc[4];
      #pragma unroll
      for (int mt=0; mt<4; mt++) acc[mt] = (f32x4){0.f,0.f,0.f,0.f};
      const hf* hrow = hcur + c*SK + q*8;
      #pragma unroll
      for (int kc=0; kc<8; kc++){
        hf8 bfrag = *(const hf8*)(hrow + kc*32);
        #pragma unroll
        for (int mt=0; mt<4; mt++)
          acc[mt] = __builtin_amdgcn_mfma_f32_16x16x32_f16(
              __builtin_bit_cast(hf8, afr[mt*8+kc]), bfrag, acc[mt], 0,0,0);
      }
      #pragma unroll
      for (int mt=0; mt<4; mt++){
        float4 xv = xwp[cur][mt];
        float xa[4] = {xv.x, xv.y, xv.z, xv.w};
        hf4 hh;
        #pragma unroll
        for (int r=0; r<4; r++){
          float v = acc[mt][r] + xa[r];
          float e2 = fast_exp2(v*C2L);
          hh[r] = (hf)(1.f - 2.f*fast_rcp(e2 + 1.f));
        }
        *(hf4*)&hnxt[c*SK + jw + mt*16 + q*4] = hh;
        *(hf4*)&H[(long)(t*512 + bb0 + c)*256 + jw + mt*16 + q*4] = hh;
      }
      sync_lds_only();
    }
  } else {
    // =================== PRE path (P-GEMM, MODE2, K=128) ===================
    constexpr int SA = 136;
    hf* As = (hf*)smem;                   // 64*SA
    hf* Bs = (hf*)smem + 64*SA;           // 128*SA
    const int bx = blockIdx.x - 32;

    float br[8];
    #pragma unroll
    for (int ni=0; ni<8; ni++) br[ni] = b1[ni*16 + c];

    f32x4 acc[8];
    #pragma unroll
    for (int ni=0; ni<8; ni++) acc[ni] = (f32x4){0.f,0.f,0.f,0.f};

    {
      const float* A = data + (long)(bx>>1)*16384;
      const int i0 = (bx & 1)*64;
      #pragma unroll
      for (int v=0; v<8; v++){
        int f4 = v*256 + tid;
        int t = f4 >> 4, i4 = (f4 & 15)*4;
        float4 d = *(const float4*)&A[t*128 + i0 + i4];
        As[(i4+0)*SA + t] = (hf)d.x;
        As[(i4+1)*SA + t] = (hf)d.y;
        As[(i4+2)*SA + t] = (hf)d.z;
        As[(i4+3)*SA + t] = (hf)d.w;
      }
      #pragma unroll
      for (int v=0; v<8; v++){
        int f8 = v*256 + tid;
        int n = f8 >> 4, k8 = (f8 & 15)*8;
        *(hf8*)&Bs[n*SA + k8] = *(const hf8*)&W1t[n*128 + k8];
      }
    }
    __syncthreads();
    #pragma unroll
    for (int kk=0; kk<4; kk++){
      hf8 a = *(const hf8*)&As[(w*16 + c)*SA + kk*32 + q*8];
      #pragma unroll
      for (int ni=0; ni<8; ni++){
        hf8 b = *(const hf8*)&Bs[(ni*16 + c)*SA + kk*32 + q*8];
        acc[ni] = __builtin_amdgcn_mfma_f32_16x16x32_f16(a, b, acc[ni], 0, 0, 0);
      }
    }
    #pragma unroll
    for (int ni=0; ni<8; ni++){
      #pragma unroll
      for (int r=0; r<4; r++){
        int rloc = w*16 + q*4 + r;
        int col = ni*16 + c;
        int b_ = bx >> 1, i_ = (bx & 1)*64 + rloc;
        P[b_*16384 + i_*128 + col] = fast_exp2(C2L*(acc[ni][r] + br[ni]));
      }
    }
  }
}

// ---------------- attention: fused Q-GEMM + softmax + scale ----------------
// grid (512 b, 4 t-tiles), 256 thr (4 waves), __launch_bounds__(256,4).
__global__ __launch_bounds__(256, 4) void k_attn(const float* __restrict__ P,
    const hf* __restrict__ H, const hf* __restrict__ W2t,
    const float* __restrict__ b2, const float* __restrict__ Wv,
    const float* __restrict__ data, float* __restrict__ out){
  __shared__ alignas(16) unsigned char hq[32*264*2];  // Hs (16.9KB) / qs (16KB)
  __shared__ alignas(16) float wvs[128];
  __shared__ alignas(16) float epart[2][2][4][128];   // 16KB
  __shared__ float red[2][4][2];
  hf* Hs = (hf*)hq;
  float* qs = (float*)hq;
  constexpr int SH = 264;
  const int b = blockIdx.x, tile = blockIdx.y;
  const int tid = threadIdx.x;
  const int w = tid >> 6, lane = tid & 63;
  const int c = lane & 15, q = lane >> 4;
  const int i = tid & 127, hl = tid >> 7;
  const int t0 = tile*32;
  if (tid < 128) wvs[tid] = -2.f*Wv[tid];
  {
    int tt = tid >> 3, seg = (tid & 7)*32;
    const hf* src = H + (long)((t0+tt)*512 + b)*256 + seg;
    #pragma unroll
    for (int v=0; v<4; v++)
      *(hf8*)&Hs[tt*SH + seg + v*8] = *(const hf8*)&src[v*8];
  }
  __syncthreads();
  const int mt = w & 1, ng = (w >> 1)*4;    // Q-GEMM: M=32 x N=128 x K=256
  float b2v[4];
  #pragma unroll
  for (int ntl=0; ntl<4; ntl++) b2v[ntl] = b2[(ng+ntl)*16 + c];
  f32x4 qacc[4];
  #pragma unroll
  for (int ntl=0; ntl<4; ntl++) qacc[ntl] = (f32x4){0.f,0.f,0.f,0.f};
  #pragma unroll
  for (int kc=0; kc<8; kc++){
    hf8 a = *(const hf8*)&Hs[(mt*16 + c)*SH + kc*32 + q*8];
    #pragma unroll
    for (int ntl=0; ntl<4; ntl++){
      hf8 bf = *(const hf8*)&W2t[((ng+ntl)*16 + c)*256 + kc*32 + q*8];
      qacc[ntl] = __builtin_amdgcn_mfma_f32_16x16x32_f16(a, bf, qacc[ntl], 0,0,0);
    }
  }
  __syncthreads();                          // Hs reads complete
  #pragma unroll
  for (int ntl=0; ntl<4; ntl++){
    #pragma unroll
    for (int r=0; r<4; r++){
      int tloc = mt*16 + q*4 + r;
      int tau = (ng+ntl)*16 + c;
      qs[tloc*128 + tau] = fast_exp2(C2L*(qacc[ntl][r] + b2v[ntl]));
    }
  }
  float4 p4[16];
  const float* prow = P + b*16384 + i*128 + hl*64;
  #pragma unroll
  for (int v=0; v<16; v++) p4[v] = *(const float4*)&prow[v*4];
  __syncthreads();
  for (int tp=0; tp<8; tp++){
    const int pp = tp & 1;
    const float* q0r = &qs[(4*tp)*128   + hl*64];
    const float* q1r = &qs[(4*tp+1)*128 + hl*64];
    const float* q2r = &qs[(4*tp+2)*128 + hl*64];
    const float* q3r = &qs[(4*tp+3)*128 + hl*64];
    const float* wvr = &wvs[hl*64];
    float acc0=0.f, acc1=0.f, acc2=0.f, acc3=0.f;
    #pragma unroll
    for (int m=0; m<16; m++){
      float4 Pv = p4[m];
      float4 wv = *(const float4*)&wvr[m*4];
      {
        float4 qq = *(const float4*)&q0r[m*4];
        float u = fmaf(Pv.x, qq.x, 1.f), v = fmaf(Pv.y, qq.y, 1.f);
        float n = fmaf(wv.x, v, wv.y*u);
        acc0 = fmaf(n, fast_rcp(u*v), acc0);
        float u2 = fmaf(Pv.z, qq.z, 1.f), v2 = fmaf(Pv.w, qq.w, 1.f);
        float n2 = fmaf(wv.z, v2, wv.w*u2);
        acc0 = fmaf(n2, fast_rcp(u2*v2), acc0);
      }
      {
        float4 qq = *(const float4*)&q1r[m*4];
        float u = fmaf(Pv.x, qq.x, 1.f), v = fmaf(Pv.y, qq.y, 1.f);
        float n = fmaf(wv.x, v, wv.y*u);
        acc1 = fmaf(n, fast_rcp(u*v), acc1);
        float u2 = fmaf(Pv.z, qq.z, 1.f), v2 = fmaf(Pv.w, qq.w, 1.f);
        float n2 = fmaf(wv.z, v2, wv.w*u2);
        acc1 = fmaf(n2, fast_rcp(u2*v2), acc1);
      }
      {
        float4 qq = *(const float4*)&q2r[m*4];
        float u = fmaf(Pv.x, qq.x, 1.f), v = fmaf(Pv.y, qq.y, 1.f);
        float n = fmaf(wv.x, v, wv.y*u);
        acc2 = fmaf(n, fast_rcp(u*v), acc2);
        float u2 = fmaf(Pv.z, qq.z, 1.f), v2 = fmaf(Pv.w, qq.w, 1.f);
        float n2 = fmaf(wv.z, v2, wv.w*u2);
        acc2 = fmaf(n2, fast_rcp(u2*v2), acc2);
      }
      {
        float4 qq = *(const float4*)&q3r[m*4];
        float u = fmaf(Pv.x, qq.x, 1.f), v = fmaf(Pv.y, qq.y, 1.f);
        float n = fmaf(wv.x, v, wv.y*u);
        acc3 = fmaf(n, fast_rcp(u*v), acc3);
        float u2 = fmaf(Pv.z, qq.z, 1.f), v2 = fmaf(Pv.w, qq.w, 1.f);
        float n2 = fmaf(wv.z, v2, wv.w*u2);
        acc3 = fmaf(n2, fast_rcp(u2*v2), acc3);
      }
    }
    epart[pp][hl][0][i] = acc0;
    epart[pp][hl][1][i] = acc1;
    epart[pp][hl][2][i] = acc2;
    epart[pp][hl][3][i] = acc3;
    __syncthreads();
    const int g = tid >> 7;
    float pe[2];
    #pragma unroll
    for (int s=0; s<2; s++){
      int tl = g + 2*s;
      float e = epart[pp][0][tl][i] + epart[pp][1][tl][i];
      pe[s] = fast_exp2(e*L2E);
      float sm = pe[s];
      #pragma unroll
      for (int off=32; off; off>>=1) sm += __shfl_xor(sm, off);
      if ((tid & 63) == 0) red[pp][tl][(tid>>6)&1] = sm;
    }
    __syncthreads();
    #pragma unroll
    for (int s=0; s<2; s++){
      int tl = g + 2*s;
      float ssum = red[pp][tl][0] + red[pp][tl][1];
      float alpha = pe[s] * fast_rcp(ssum);
      int t = t0 + 4*tp + tl;
      int base = (t*512 + b)*128 + i;
      out[base] = data[base]*alpha;
    }
  }
}

extern "C" void kernel_launch(void* const* d_in, const int* in_sizes, int n_in,
                              void* d_out, int out_size, void* d_ws, size_t ws_size,
                              hipStream_t stream) {
  const float* data = (const float*)d_in[0];
  const float* h0   = (const float*)d_in[1];
  const float* Wx   = (const float*)d_in[2];
  const float* Wh   = (const float*)d_in[3];
  const float* bb   = (const float*)d_in[4];
  const float* W1   = (const float*)d_in[5];
  const float* b1   = (const float*)d_in[6];
  const float* W2   = (const float*)d_in[7];
  const float* b2   = (const float*)d_in[8];
  const float* Wv   = (const float*)d_in[9];
  // d_in[10] = bv: softmax-invariant constant, dropped. d_in[11] = n (128).
  float* wsp = (float*)d_ws;
  float* P    = wsp;                        //  8,388,608 f
  float* xw   = wsp + 8388608;              // 16,777,216 f
  hf*    Hbuf = (hf*)(wsp + 25165824);      // 16,777,216 hf
  hf*    wts  = (hf*)(wsp + 33554432);      // 147,456 hf
  hf*    Wxt  = wts;                        // [256][128]
  hf*    W2t  = wts + 32768;                // [128][256]
  hf*    W1t  = wts + 65536;                // [128][128]
  hf*    Wht  = wts + 81920;                // [256][256]
  float* out = (float*)d_out;

  hipLaunchKernelGGL(k_prep_w, dim3(576), dim3(256), 0, stream, Wx, W2, W1, Wh, wts);
  hipLaunchKernelGGL((k_gemm<128,0>), dim3(1024,2), dim3(256), 0, stream,
                     (const void*)data, Wxt, bb, xw);
  hipLaunchKernelGGL(k_rnn_pre, dim3(1056), dim3(256), 0, stream,
                     h0, Wht, xw, Hbuf, data, W1t, b1, P);
  hipLaunchKernelGGL(k_attn, dim3(512, 4), dim3(256), 0, stream,
                     P, Hbuf, W2t, b2, Wv, data, out);
}